// Round 10
// baseline (1180.198 us; speedup 1.0000x reference)
//
#include <hip/hip_runtime.h>
#include <stdint.h>

#define DEV static __device__ __forceinline__

typedef unsigned short u16;
typedef float  f32x4  __attribute__((ext_vector_type(4)));
typedef float  f32x16 __attribute__((ext_vector_type(16)));
typedef short  s16x8  __attribute__((ext_vector_type(8)));
typedef u16    u16x4  __attribute__((ext_vector_type(4)));

#define VMCNT(n) asm volatile("s_waitcnt vmcnt(" #n ")" ::: "memory")
#define BAR() __builtin_amdgcn_s_barrier()

// round-to-nearest-even f32 -> bf16 bits
DEV u16 f2bf(float f) {
  uint32_t u = __float_as_uint(f);
  u += 0x7FFFu + ((u >> 16) & 1u);
  return (u16)(u >> 16);
}

// async global->LDS, 16 bytes per lane
DEV void async16(const void* g, void* l) {
  __builtin_amdgcn_global_load_lds(
      (const __attribute__((address_space(1))) void*)g,
      (__attribute__((address_space(3))) void*)l, 16, 0, 0);
}

// ---------------- router ----------------
__global__ void route_zero(int* c) {
  if (threadIdx.x < 8) c[threadIdx.x] = 0;
}
__global__ void route_count(const int* __restrict__ k, int* __restrict__ c, int B) {
  int i = blockIdx.x * blockDim.x + threadIdx.x;
  if (i < B) atomicAdd(&c[k[i]], 1);
}
__global__ void route_scan(int* c) {
  if (threadIdx.x == 0) {
    int s = 0;
    for (int e = 0; e < 4; ++e) { c[8 + e] = s; s += c[e]; }
  }
}
__global__ void route_scatter(const int* __restrict__ k, int* __restrict__ c,
                              int* __restrict__ perm, int B) {
  int i = blockIdx.x * blockDim.x + threadIdx.x;
  if (i < B) {
    int e = k[i];
    int pos = atomicAdd(&c[4 + e], 1);
    perm[c[8 + e] + pos] = i;
  }
}

// ---------------- conversions ----------------
__global__ void cvt_f32_bf16(const float* __restrict__ src, u16* __restrict__ dst, long n4) {
  long i = (long)blockIdx.x * blockDim.x + threadIdx.x;
  long stride = (long)gridDim.x * blockDim.x;
  for (; i < n4; i += stride) {
    f32x4 v = ((const f32x4*)src)[i];
    u16x4 o;
    o.x = f2bf(v.x); o.y = f2bf(v.y); o.z = f2bf(v.z); o.w = f2bf(v.w);
    ((u16x4*)dst)[i] = o;
  }
}

// src [z][R][C] f32  ->  dst [z][C][R] bf16
__global__ void transpose_w(const float* __restrict__ src, u16* __restrict__ dst,
                            int R, int C) {
  __shared__ float t[32][33];
  long base = (long)blockIdx.z * R * C;
  int c0 = blockIdx.x * 32, r0 = blockIdx.y * 32;
  int tx = threadIdx.x, ty = threadIdx.y;  // (32,8)
#pragma unroll
  for (int i = 0; i < 32; i += 8)
    t[ty + i][tx] = src[base + (long)(r0 + ty + i) * C + c0 + tx];
  __syncthreads();
#pragma unroll
  for (int i = 0; i < 32; i += 8)
    dst[base + (long)(c0 + ty + i) * R + r0 + tx] = f2bf(t[tx][ty + i]);
}

// ======== 256x256 8-phase / 2-K-tile GEMM, 32x32x16 MFMA ========
// Skeleton/staging/ledger identical to the verified round-7/9 kernel:
// 512 threads = 8 waves (2M x 4N), per-wave 128x64. BK=64. LDS 128KB.
// Rows 128B, XOR swizzle byte ^= (row&7)<<4 (inverse on global source);
// stage schedule P1 Ah1(t+1), P2 Ah0(t+2), P3 Bh0(t+2), P4 Bh1(t+2)
// + vmcnt(6), mirrored. Shape change only: v_mfma_f32_32x32x16_bf16
// (2382 vs 2075 TF ceiling) -> MFMA-pipe cycles/K-tile -15%.
// Frags: aa[2][4] (two 32-row m-frags x 4 ksteps), bn0/bn1[4]. acc[4][2] f32x16.
// C/D layout (HW-verified m74/m101): col=lane&31, row=(reg&3)+8*(reg>>2)+4*(lane>>5).

DEV void stageA(const u16* __restrict__ A, long K, long bm, int k0, int g,
                u16* lds, int tid) {
#pragma unroll
  for (int j = 0; j < 2; ++j) {
    int i = j * 512 + tid;
    int row = ((i >> 9) << 7) | (g << 6) | ((i >> 3) & 63);
    int p = (i & 7) * 16;                  // phys byte-in-row
    int ke = (p ^ ((row & 7) << 4)) >> 1;  // logical k element (inverse swizzle)
    async16(A + (bm + row) * K + k0 + ke, lds + row * 64 + (i & 7) * 8);
  }
}

DEV void stageB(const u16* __restrict__ Bt, long K, long bn, int k0, int g,
                u16* lds, int tid) {
#pragma unroll
  for (int j = 0; j < 2; ++j) {
    int i = j * 512 + tid;
    int col = ((i >> 8) << 6) | (g << 5) | ((i >> 3) & 31);
    int p = (i & 7) * 16;
    int ke = (p ^ ((col & 7) << 4)) >> 1;
    async16(Bt + (bn + col) * K + k0 + ke, lds + col * 64 + (i & 7) * 8);
  }
}

// gathered A staging: per-thread global rows preloaded (ar[j]), LDS row from tid
DEV void stageAg(const u16* __restrict__ X, long K, int k0, int g,
                 const long* ar, u16* lds, int tid) {
#pragma unroll
  for (int j = 0; j < 2; ++j) {
    int i = j * 512 + tid;
    int row = (j << 7) | (g << 6) | ((i >> 3) & 63);
    int p = (i & 7) * 16;
    int ke = (p ^ ((row & 7) << 4)) >> 1;
    async16(X + ar[j] * K + k0 + ke, lds + row * 64 + (i & 7) * 8);
  }
}

// 32x32x16 fragment read: lane holds row=base+(lane&31), k-half hk=lane>>5.
// byte = (ks*32 + hk*16) ^ ((row&7)<<4); per-8-lane slot map is an XOR
// bijection -> conflict-free (same family as the measured-0 pattern).
DEV s16x8 ldf32(const u16* lds, int row, int ks, int hk) {
  int b = (ks * 32 + hk * 16) ^ ((row & 7) << 4);
  return *(const s16x8*)((const char*)(lds + row * 64) + b);
}

// one K-tile = 4 phases; S1..S4 = per-phase stage statements; 1 bar/phase.
// P1: 12 reads, MFMA mf0-1 x n0; P2: 4 reads, mf0-1 x n1;
// P3: 8 reads (aa reused for mf2-3), x n0; P4: 0 reads + vmcnt(6), x n1.
#define KT432(Ac, Bc, S1, S2, S3, S4)                                          \
  {                                                                            \
    _Pragma("unroll") for (int mf = 0; mf < 2; ++mf)                           \
      _Pragma("unroll") for (int ks = 0; ks < 4; ++ks)                         \
        aa[mf][ks] = ldf32(Ac, wr * 128 + mf * 32 + lr32, ks, hk);             \
    _Pragma("unroll") for (int ks = 0; ks < 4; ++ks)                           \
      bn0[ks] = ldf32(Bc, wc * 64 + lr32, ks, hk);                             \
    S1;                                                                        \
    BAR();                                                                     \
    __builtin_amdgcn_s_setprio(1);                                             \
    _Pragma("unroll") for (int mf = 0; mf < 2; ++mf)                           \
      _Pragma("unroll") for (int ks = 0; ks < 4; ++ks)                         \
        acc[mf][0] = __builtin_amdgcn_mfma_f32_32x32x16_bf16(                  \
            aa[mf][ks], bn0[ks], acc[mf][0], 0, 0, 0);                         \
    __builtin_amdgcn_s_setprio(0);                                             \
    _Pragma("unroll") for (int ks = 0; ks < 4; ++ks)                           \
      bn1[ks] = ldf32(Bc, wc * 64 + 32 + lr32, ks, hk);                        \
    S2;                                                                        \
    BAR();                                                                     \
    __builtin_amdgcn_s_setprio(1);                                             \
    _Pragma("unroll") for (int mf = 0; mf < 2; ++mf)                           \
      _Pragma("unroll") for (int ks = 0; ks < 4; ++ks)                         \
        acc[mf][1] = __builtin_amdgcn_mfma_f32_32x32x16_bf16(                  \
            aa[mf][ks], bn1[ks], acc[mf][1], 0, 0, 0);                         \
    __builtin_amdgcn_s_setprio(0);                                             \
    _Pragma("unroll") for (int mf = 0; mf < 2; ++mf)                           \
      _Pragma("unroll") for (int ks = 0; ks < 4; ++ks)                         \
        aa[mf][ks] = ldf32(Ac, wr * 128 + (mf + 2) * 32 + lr32, ks, hk);       \
    S3;                                                                        \
    BAR();                                                                     \
    __builtin_amdgcn_s_setprio(1);                                             \
    _Pragma("unroll") for (int mf = 0; mf < 2; ++mf)                           \
      _Pragma("unroll") for (int ks = 0; ks < 4; ++ks)                         \
        acc[mf + 2][0] = __builtin_amdgcn_mfma_f32_32x32x16_bf16(              \
            aa[mf][ks], bn0[ks], acc[mf + 2][0], 0, 0, 0);                     \
    __builtin_amdgcn_s_setprio(0);                                             \
    S4;                                                                        \
    VMCNT(6);                                                                  \
    BAR();                                                                     \
    __builtin_amdgcn_s_setprio(1);                                             \
    _Pragma("unroll") for (int mf = 0; mf < 2; ++mf)                           \
      _Pragma("unroll") for (int ks = 0; ks < 4; ++ks)                         \
        acc[mf + 2][1] = __builtin_amdgcn_mfma_f32_32x32x16_bf16(              \
            aa[mf][ks], bn1[ks], acc[mf + 2][1], 0, 0, 0);                     \
    __builtin_amdgcn_s_setprio(0);                                             \
  }

template <int RELU, int OUTF32>
__global__ __launch_bounds__(512, 2) void gemm256p(
    const u16* __restrict__ A, const u16* __restrict__ Bt,
    const float* __restrict__ bias, void* __restrict__ Cout, int N, int K) {
  __shared__ u16 Al[2][256 * 64];
  __shared__ u16 Bl[2][256 * 64];
  const int tid = threadIdx.x;
  const int lane = tid & 63, wid = tid >> 6;
  const int wr = wid >> 2, wc = wid & 3;  // 2 x 4 wave grid
  const int lr32 = lane & 31, hk = lane >> 5;

  // XCD-aware bijective swizzle (grids all % 8 == 0; guarded)
  const int nby = N >> 8;
  const int nwg = gridDim.x;
  int wg = blockIdx.x;
  if ((nwg & 7) == 0) {
    const int q = nwg >> 3;
    wg = (wg & 7) * q + (wg >> 3);
  }
  const long bm = (long)(wg / nby) << 8;
  const long bn = (long)(wg % nby) << 8;

  const int nt = K >> 6;  // even (>=16) for all K used here
  f32x16 acc[4][2] = {};
  s16x8 aa[2][4], bn0[4], bn1[4];

  // prologue: tile0 fully + tile1 halves Ah0,Bh0,Bh1 (Ah1(1) staged at P1)
  stageA(A, K, bm, 0, 0, Al[0], tid);
  stageB(Bt, K, bn, 0, 0, Bl[0], tid);
  stageB(Bt, K, bn, 0, 1, Bl[0], tid);
  stageA(A, K, bm, 0, 1, Al[0], tid);
  stageA(A, K, bm, 64, 0, Al[1], tid);
  stageB(Bt, K, bn, 64, 0, Bl[1], tid);
  stageB(Bt, K, bn, 64, 1, Bl[1], tid);
  VMCNT(6);  // drains tile0's 8 loads; leaves tile1's 3 halves (steady state)
  BAR();

  const int ni = nt >> 1;
  for (int i2 = 0; i2 < ni; ++i2) {
    const int t0 = 2 * i2;
    const int kn1 = (t0 + 1) << 6;  // fresh stage of Ah1(t+1)
    const int kn2 = ((t0 + 2 < nt) ? t0 + 2 : t0) << 6;       // clamped re-stage
    const int kn3 = ((t0 + 3 < nt) ? t0 + 3 : t0 + 1) << 6;
    KT432(Al[0], Bl[0],
          stageA(A, K, bm, kn1, 1, Al[1], tid),
          stageA(A, K, bm, kn2, 0, Al[0], tid),
          stageB(Bt, K, bn, kn2, 0, Bl[0], tid),
          stageB(Bt, K, bn, kn2, 1, Bl[0], tid));
    KT432(Al[1], Bl[1],
          stageA(A, K, bm, kn2, 1, Al[0], tid),
          stageA(A, K, bm, kn3, 0, Al[1], tid),
          stageB(Bt, K, bn, kn3, 0, Bl[1], tid),
          stageB(Bt, K, bn, kn3, 1, Bl[1], tid));
  }

  // epilogue: bias + activation + store (32x32 C/D layout)
#pragma unroll
  for (int mf = 0; mf < 4; ++mf) {
#pragma unroll
    for (int nf = 0; nf < 2; ++nf) {
      const long col = bn + wc * 64 + nf * 32 + lr32;
      const float bv = bias[col];
#pragma unroll
      for (int r = 0; r < 16; ++r) {
        const long row = bm + wr * 128 + mf * 32 + (r & 3) + 8 * (r >> 2) + 4 * hk;
        float v = acc[mf][nf][r] + bv;
        if (RELU) v = fmaxf(v, 0.0f);
        if (OUTF32) ((float*)Cout)[row * (long)N + col] = v;
        else        ((u16*)Cout)[row * (long)N + col] = f2bf(v);
      }
    }
  }
}

// ======== gathered expert GEMM, same structure ========
__global__ __launch_bounds__(512, 2) void gemm256e(
    const u16* __restrict__ X, const u16* __restrict__ Wt,
    const float* __restrict__ bexp, u16* __restrict__ Out,
    const int* __restrict__ perm, const int* __restrict__ cvec,
    int K, int N, int TPE) {
  __shared__ u16 Al[2][256 * 64];
  __shared__ u16 Bl[2][256 * 64];
  const int e = blockIdx.x / TPE;
  const int tile = blockIdx.x - e * TPE;
  const int cnt = cvec[e];
  if (tile * 256 >= cnt) return;
  const int start = cvec[8 + e];

  const int tid = threadIdx.x;
  const int lane = tid & 63, wid = tid >> 6;
  const int wr = wid >> 2, wc = wid & 3;
  const int lr32 = lane & 31, hk = lane >> 5;
  const long bn = (long)blockIdx.y << 8;
  const long wbase = (long)e * N;  // weight row base for this expert

  // preload gathered A-row indices (fixed per thread)
  long ar[2][2];
#pragma unroll
  for (int g = 0; g < 2; ++g)
#pragma unroll
    for (int j = 0; j < 2; ++j) {
      int rie = tile * 256 + ((j << 7) | (g << 6) | ((tid >> 3) & 63));
      ar[g][j] = perm[start + (rie < cnt - 1 ? rie : cnt - 1)];
    }

  const int nt = K >> 6;  // K=2048 -> 32, even
  f32x16 acc[4][2] = {};
  s16x8 aa[2][4], bn0[4], bn1[4];

  stageAg(X, K, 0, 0, ar[0], Al[0], tid);
  stageB(Wt, K, wbase + bn, 0, 0, Bl[0], tid);
  stageB(Wt, K, wbase + bn, 0, 1, Bl[0], tid);
  stageAg(X, K, 0, 1, ar[1], Al[0], tid);
  stageAg(X, K, 64, 0, ar[0], Al[1], tid);
  stageB(Wt, K, wbase + bn, 64, 0, Bl[1], tid);
  stageB(Wt, K, wbase + bn, 64, 1, Bl[1], tid);
  VMCNT(6);
  BAR();

  const int ni = nt >> 1;
  for (int i2 = 0; i2 < ni; ++i2) {
    const int t0 = 2 * i2;
    const int kn1 = (t0 + 1) << 6;
    const int kn2 = ((t0 + 2 < nt) ? t0 + 2 : t0) << 6;
    const int kn3 = ((t0 + 3 < nt) ? t0 + 3 : t0 + 1) << 6;
    KT432(Al[0], Bl[0],
          stageAg(X, K, kn1, 1, ar[1], Al[1], tid),
          stageAg(X, K, kn2, 0, ar[0], Al[0], tid),
          stageB(Wt, K, wbase + bn, kn2, 0, Bl[0], tid),
          stageB(Wt, K, wbase + bn, kn2, 1, Bl[0], tid));
    KT432(Al[1], Bl[1],
          stageAg(X, K, kn2, 1, ar[1], Al[0], tid),
          stageAg(X, K, kn3, 0, ar[0], Al[1], tid),
          stageB(Wt, K, wbase + bn, kn3, 0, Bl[1], tid),
          stageB(Wt, K, wbase + bn, kn3, 1, Bl[1], tid));
  }

  // epilogue: bias + scatter via perm (guard rb < cnt), 32x32 C/D layout
#pragma unroll
  for (int mf = 0; mf < 4; ++mf) {
#pragma unroll
    for (int r = 0; r < 16; ++r) {
      const int rb = tile * 256 + wr * 128 + mf * 32 + (r & 3) + 8 * (r >> 2) + 4 * hk;
      if (rb < cnt) {
        const long grow = perm[start + rb];
#pragma unroll
        for (int nf = 0; nf < 2; ++nf) {
          const long col = bn + wc * 64 + nf * 32 + lr32;
          float v = acc[mf][nf][r] + bexp[wbase + col];
          Out[grow * (long)N + col] = f2bf(v);
        }
      }
    }
  }
}

// ---------------- launch ----------------
extern "C" void kernel_launch(void* const* d_in, const int* in_sizes, int n_in,
                              void* d_out, int out_size, void* d_ws, size_t ws_size,
                              hipStream_t stream) {
  const float* x     = (const float*)d_in[0];
  const int*   kk    = (const int*)d_in[1];
  const float* W_exp = (const float*)d_in[2];
  const float* b_exp = (const float*)d_in[3];
  const float* W1    = (const float*)d_in[4];
  const float* b1    = (const float*)d_in[5];
  const float* W2    = (const float*)d_in[6];
  const float* b2    = (const float*)d_in[7];
  const float* W3    = (const float*)d_in[8];
  const float* b3    = (const float*)d_in[9];
  float* out = (float*)d_out;

  const int B = 16384, DIN = 2048, DC = 1024, H = 4096, DOUT = 1024, E = 4;

  uint8_t* ws = (uint8_t*)d_ws;
  const size_t MB = 1ull << 20;
  u16* xb    = (u16*)(ws + 0);         // 64MB  [B][2048]
  u16* algn  = (u16*)(ws + 64 * MB);   // 32MB  [B][1024]
  u16* h2    = (u16*)(ws + 0);         // 128MB [B][4096] (reuses xb+algn, live later)
  u16* h1    = (u16*)(ws + 128 * MB);  // 128MB [B][4096]
  u16* wexpt = (u16*)(ws + 256 * MB);  // 16MB  [4][1024][2048]
  u16* w1t   = (u16*)(ws + 272 * MB);  // 8MB   [4096][1024]
  u16* w2t   = (u16*)(ws + 280 * MB);  // 32MB  [4096][4096]
  u16* w3t   = (u16*)(ws + 312 * MB);  // 8MB   [1024][4096]
  int* perm  = (int*)(ws + 320 * MB);  // 64KB
  int* cvec  = (int*)(ws + 320 * MB + 65536);

  // router
  route_zero<<<1, 64, 0, stream>>>(cvec);
  route_count<<<(B + 255) / 256, 256, 0, stream>>>(kk, cvec, B);
  route_scan<<<1, 64, 0, stream>>>(cvec);
  route_scatter<<<(B + 255) / 256, 256, 0, stream>>>(kk, cvec, perm, B);

  // conversions
  cvt_f32_bf16<<<2048, 256, 0, stream>>>(x, xb, (long)B * DIN / 4);
  dim3 tb(32, 8);
  transpose_w<<<dim3(DC / 32, DIN / 32, E), tb, 0, stream>>>(W_exp, wexpt, DIN, DC);
  transpose_w<<<dim3(H / 32, DC / 32, 1), tb, 0, stream>>>(W1, w1t, DC, H);
  transpose_w<<<dim3(H / 32, H / 32, 1), tb, 0, stream>>>(W2, w2t, H, H);
  transpose_w<<<dim3(DOUT / 32, H / 32, 1), tb, 0, stream>>>(W3, w3t, H, DOUT);

  // expert projection (gathered, 256^2 8-phase, 32x32 MFMA)
  const int TPE = B / 256;
  gemm256e<<<dim3(E * TPE, DC / 256), 512, 0, stream>>>(
      xb, wexpt, b_exp, algn, perm, cvec, DIN, DC, TPE);

  // dense MLP (32x32 MFMA)
  gemm256p<1, 0><<<dim3((B / 256) * (H / 256)), 512, 0, stream>>>(algn, w1t, b1, h1, H, DC);
  gemm256p<1, 0><<<dim3((B / 256) * (H / 256)), 512, 0, stream>>>(h1, w2t, b2, h2, H, H);
  gemm256p<0, 1><<<dim3((B / 256) * (DOUT / 256)), 512, 0, stream>>>(h2, w3t, b3, out, DOUT, H);
}

// Round 11
// 1099.574 us; speedup vs baseline: 1.0733x; 1.0733x over previous
//
#include <hip/hip_runtime.h>
#include <stdint.h>

#define DEV static __device__ __forceinline__

typedef unsigned short u16;
typedef float  f32x4 __attribute__((ext_vector_type(4)));
typedef short  s16x8 __attribute__((ext_vector_type(8)));
typedef u16    u16x4 __attribute__((ext_vector_type(4)));

#define VMCNT(n) asm volatile("s_waitcnt vmcnt(" #n ")" ::: "memory")
#define BAR() __builtin_amdgcn_s_barrier()
#define MFMA16(d, va, vb) d = __builtin_amdgcn_mfma_f32_16x16x32_bf16(va, vb, d, 0, 0, 0)

// round-to-nearest-even f32 -> bf16 bits
DEV u16 f2bf(float f) {
  uint32_t u = __float_as_uint(f);
  u += 0x7FFFu + ((u >> 16) & 1u);
  return (u16)(u >> 16);
}

// async global->LDS, 16 bytes per lane
DEV void async16(const void* g, void* l) {
  __builtin_amdgcn_global_load_lds(
      (const __attribute__((address_space(1))) void*)g,
      (__attribute__((address_space(3))) void*)l, 16, 0, 0);
}

// ---------------- router ----------------
__global__ void route_zero(int* c) {
  if (threadIdx.x < 8) c[threadIdx.x] = 0;
}
__global__ void route_count(const int* __restrict__ k, int* __restrict__ c, int B) {
  int i = blockIdx.x * blockDim.x + threadIdx.x;
  if (i < B) atomicAdd(&c[k[i]], 1);
}
__global__ void route_scan(int* c) {
  if (threadIdx.x == 0) {
    int s = 0;
    for (int e = 0; e < 4; ++e) { c[8 + e] = s; s += c[e]; }
  }
}
__global__ void route_scatter(const int* __restrict__ k, int* __restrict__ c,
                              int* __restrict__ perm, int B) {
  int i = blockIdx.x * blockDim.x + threadIdx.x;
  if (i < B) {
    int e = k[i];
    int pos = atomicAdd(&c[4 + e], 1);
    perm[c[8 + e] + pos] = i;
  }
}

// ---------------- conversions ----------------
__global__ void cvt_f32_bf16(const float* __restrict__ src, u16* __restrict__ dst, long n4) {
  long i = (long)blockIdx.x * blockDim.x + threadIdx.x;
  long stride = (long)gridDim.x * blockDim.x;
  for (; i < n4; i += stride) {
    f32x4 v = ((const f32x4*)src)[i];
    u16x4 o;
    o.x = f2bf(v.x); o.y = f2bf(v.y); o.z = f2bf(v.z); o.w = f2bf(v.w);
    ((u16x4*)dst)[i] = o;
  }
}

// src [z][R][C] f32  ->  dst [z][C][R] bf16
__global__ void transpose_w(const float* __restrict__ src, u16* __restrict__ dst,
                            int R, int C) {
  __shared__ float t[32][33];
  long base = (long)blockIdx.z * R * C;
  int c0 = blockIdx.x * 32, r0 = blockIdx.y * 32;
  int tx = threadIdx.x, ty = threadIdx.y;  // (32,8)
#pragma unroll
  for (int i = 0; i < 32; i += 8)
    t[ty + i][tx] = src[base + (long)(r0 + ty + i) * C + c0 + tx];
  __syncthreads();
#pragma unroll
  for (int i = 0; i < 32; i += 8)
    dst[base + (long)(c0 + ty + i) * R + r0 + tx] = f2bf(t[tx][ty + i]);
}

// ======== 256x256 8-phase GEMM, reads-early schedule, 4Mx2N waves ========
// A [M][K] bf16, Bt [N][K] bf16, C = act(A @ Bt^T + bias)
// 512 threads = 8 waves (4M x 2N), per-wave 64x128. BK=64. LDS 128KB.
// Rows 128B, XOR swizzle byte ^= (row&7)<<4 (inverse on global source);
// measured 0 bank conflicts (rounds 2/3/6/7/9).
// Round-11 change: wave reads its A operand (8 frags) ONCE per K-tile and
// holds it; B consumed in 4 col-pairs ping-ponged bA/bB, each pair read
// one window AHEAD (right after the barrier, before the MFMA cluster) so
// LDS latency hides under the MFMA burst instead of stalling it.
// Stage schedule & vmcnt(6) ledger identical to the verified round-7/9:
// P1 Ah1(t+1), P2 Ah0(t+2), P3 Bh0(t+2), P4 Bh1(t+2)+vmcnt(6), mirrored.

DEV void stageA(const u16* __restrict__ A, long K, long bm, int k0, int g,
                u16* lds, int tid) {
#pragma unroll
  for (int j = 0; j < 2; ++j) {
    int i = j * 512 + tid;
    int row = ((i >> 9) << 7) | (g << 6) | ((i >> 3) & 63);
    int p = (i & 7) * 16;                  // phys byte-in-row
    int ke = (p ^ ((row & 7) << 4)) >> 1;  // logical k element (inverse swizzle)
    async16(A + (bm + row) * K + k0 + ke, lds + row * 64 + (i & 7) * 8);
  }
}

DEV void stageB(const u16* __restrict__ Bt, long K, long bn, int k0, int g,
                u16* lds, int tid) {
#pragma unroll
  for (int j = 0; j < 2; ++j) {
    int i = j * 512 + tid;
    int col = ((i >> 8) << 6) | (g << 5) | ((i >> 3) & 31);
    int p = (i & 7) * 16;
    int ke = (p ^ ((col & 7) << 4)) >> 1;
    async16(Bt + (bn + col) * K + k0 + ke, lds + col * 64 + (i & 7) * 8);
  }
}

// gathered A staging: per-thread global rows preloaded (ar[j]), LDS row from tid
DEV void stageAg(const u16* __restrict__ X, long K, int k0, int g,
                 const long* ar, u16* lds, int tid) {
#pragma unroll
  for (int j = 0; j < 2; ++j) {
    int i = j * 512 + tid;
    int row = (j << 7) | (g << 6) | ((i >> 3) & 63);
    int p = (i & 7) * 16;
    int ke = (p ^ ((row & 7) << 4)) >> 1;
    async16(X + ar[j] * K + k0 + ke, lds + row * 64 + (i & 7) * 8);
  }
}

DEV s16x8 ldfrag(const u16* lds, int row, int ks, int lk) {
  int b = (ks * 64 + lk * 16) ^ ((row & 7) << 4);
  return *(const s16x8*)((const char*)(lds + row * 64) + b);
}

// One K-tile = 4 phases. Entering: a = A(t), bA = B cols nf0-1 of t.
// Each phase: [stage; (vmcnt); BAR; early-read next b-pair; MFMA x16].
// P4 additionally late-reads a' (next tile) after its MFMA cluster (WAR
// dep prevents the compiler from hoisting it above the consumers).
#define KT4(Ac, Bc, An, Bn, S1, S2, S3, S4)                                    \
  {                                                                            \
    /* P1: MFMA a x bA(nf0-1) -> acc[:,0:2]; read bB = nf2-3 */                \
    S1;                                                                        \
    BAR();                                                                     \
    _Pragma("unroll") for (int n = 0; n < 2; ++n)                              \
      _Pragma("unroll") for (int ks = 0; ks < 2; ++ks)                         \
        bB[n][ks] = ldfrag(Bc, wc * 128 + (n + 2) * 16 + lr, ks, lk);          \
    __builtin_amdgcn_s_setprio(1);                                             \
    _Pragma("unroll") for (int m = 0; m < 4; ++m)                              \
      _Pragma("unroll") for (int n = 0; n < 2; ++n)                            \
        _Pragma("unroll") for (int ks = 0; ks < 2; ++ks)                       \
          MFMA16(acc[m][n], a[m][ks], bA[n][ks]);                              \
    __builtin_amdgcn_s_setprio(0);                                             \
    /* P2: MFMA a x bB(nf2-3) -> acc[:,2:4]; read bA = nf4-5 */                \
    S2;                                                                        \
    BAR();                                                                     \
    _Pragma("unroll") for (int n = 0; n < 2; ++n)                              \
      _Pragma("unroll") for (int ks = 0; ks < 2; ++ks)                         \
        bA[n][ks] = ldfrag(Bc, wc * 128 + (n + 4) * 16 + lr, ks, lk);          \
    __builtin_amdgcn_s_setprio(1);                                             \
    _Pragma("unroll") for (int m = 0; m < 4; ++m)                              \
      _Pragma("unroll") for (int n = 0; n < 2; ++n)                            \
        _Pragma("unroll") for (int ks = 0; ks < 2; ++ks)                       \
          MFMA16(acc[m][n + 2], a[m][ks], bB[n][ks]);                          \
    __builtin_amdgcn_s_setprio(0);                                             \
    /* P3: MFMA a x bA(nf4-5) -> acc[:,4:6]; read bB = nf6-7 */                \
    S3;                                                                        \
    BAR();                                                                     \
    _Pragma("unroll") for (int n = 0; n < 2; ++n)                              \
      _Pragma("unroll") for (int ks = 0; ks < 2; ++ks)                         \
        bB[n][ks] = ldfrag(Bc, wc * 128 + (n + 6) * 16 + lr, ks, lk);          \
    __builtin_amdgcn_s_setprio(1);                                             \
    _Pragma("unroll") for (int m = 0; m < 4; ++m)                              \
      _Pragma("unroll") for (int n = 0; n < 2; ++n)                            \
        _Pragma("unroll") for (int ks = 0; ks < 2; ++ks)                       \
          MFMA16(acc[m][n + 4], a[m][ks], bA[n][ks]);                          \
    __builtin_amdgcn_s_setprio(0);                                             \
    /* P4: read bA = nf0-1 of NEXT tile (Bn, certified by vmcnt+BAR);          \
       MFMA a x bB(nf6-7) -> acc[:,6:8]; late-read a' from An */               \
    S4;                                                                        \
    VMCNT(6);                                                                  \
    BAR();                                                                     \
    _Pragma("unroll") for (int n = 0; n < 2; ++n)                              \
      _Pragma("unroll") for (int ks = 0; ks < 2; ++ks)                         \
        bA[n][ks] = ldfrag(Bn, wc * 128 + n * 16 + lr, ks, lk);                \
    __builtin_amdgcn_s_setprio(1);                                             \
    _Pragma("unroll") for (int m = 0; m < 4; ++m)                              \
      _Pragma("unroll") for (int n = 0; n < 2; ++n)                            \
        _Pragma("unroll") for (int ks = 0; ks < 2; ++ks)                       \
          MFMA16(acc[m][n + 6], a[m][ks], bB[n][ks]);                          \
    __builtin_amdgcn_s_setprio(0);                                             \
    _Pragma("unroll") for (int m = 0; m < 4; ++m)                              \
      _Pragma("unroll") for (int ks = 0; ks < 2; ++ks)                         \
        a[m][ks] = ldfrag(An, wr * 64 + m * 16 + lr, ks, lk);                  \
  }

template <int RELU, int OUTF32>
__global__ __launch_bounds__(512, 2) void gemm256p(
    const u16* __restrict__ A, const u16* __restrict__ Bt,
    const float* __restrict__ bias, void* __restrict__ Cout, int N, int K) {
  __shared__ u16 Al[2][256 * 64];
  __shared__ u16 Bl[2][256 * 64];
  const int tid = threadIdx.x;
  const int lane = tid & 63, wid = tid >> 6;
  const int wr = wid >> 1, wc = wid & 1;  // 4M x 2N wave grid
  const int lr = lane & 15, lk = lane >> 4;

  // XCD-aware bijective swizzle (grids all % 8 == 0; guarded)
  const int nby = N >> 8;
  const int nwg = gridDim.x;
  int wg = blockIdx.x;
  if ((nwg & 7) == 0) {
    const int q = nwg >> 3;
    wg = (wg & 7) * q + (wg >> 3);
  }
  const long bm = (long)(wg / nby) << 8;
  const long bn = (long)(wg % nby) << 8;

  const int nt = K >> 6;  // even (>=16) for all K used here
  f32x4 acc[4][8] = {};
  s16x8 a[4][2], bA[2][2], bB[2][2];

  // prologue: tile0 fully + tile1 halves Ah0,Bh0,Bh1 (Ah1(1) staged at P1)
  stageA(A, K, bm, 0, 0, Al[0], tid);
  stageB(Bt, K, bn, 0, 0, Bl[0], tid);
  stageB(Bt, K, bn, 0, 1, Bl[0], tid);
  stageA(A, K, bm, 0, 1, Al[0], tid);
  stageA(A, K, bm, 64, 0, Al[1], tid);
  stageB(Bt, K, bn, 64, 0, Bl[1], tid);
  stageB(Bt, K, bn, 64, 1, Bl[1], tid);
  VMCNT(6);  // drains tile0's 8 loads; leaves tile1's 3 halves (steady state)
  BAR();

  // initial frags: a = A(tile0), bA = B cols nf0-1 (tile0)
#pragma unroll
  for (int m = 0; m < 4; ++m)
#pragma unroll
    for (int ks = 0; ks < 2; ++ks)
      a[m][ks] = ldfrag(Al[0], wr * 64 + m * 16 + lr, ks, lk);
#pragma unroll
  for (int n = 0; n < 2; ++n)
#pragma unroll
    for (int ks = 0; ks < 2; ++ks)
      bA[n][ks] = ldfrag(Bl[0], wc * 128 + n * 16 + lr, ks, lk);

  const int ni = nt >> 1;
  for (int i2 = 0; i2 < ni; ++i2) {
    const int t0 = 2 * i2;
    const int kn1 = (t0 + 1) << 6;  // fresh stage of Ah1(t+1)
    const int kn2 = ((t0 + 2 < nt) ? t0 + 2 : t0) << 6;       // clamped re-stage
    const int kn3 = ((t0 + 3 < nt) ? t0 + 3 : t0 + 1) << 6;
    KT4(Al[0], Bl[0], Al[1], Bl[1],
        stageA(A, K, bm, kn1, 1, Al[1], tid),
        stageA(A, K, bm, kn2, 0, Al[0], tid),
        stageB(Bt, K, bn, kn2, 0, Bl[0], tid),
        stageB(Bt, K, bn, kn2, 1, Bl[0], tid));
    KT4(Al[1], Bl[1], Al[0], Bl[0],
        stageA(A, K, bm, kn2, 1, Al[0], tid),
        stageA(A, K, bm, kn3, 0, Al[1], tid),
        stageB(Bt, K, bn, kn3, 0, Bl[1], tid),
        stageB(Bt, K, bn, kn3, 1, Bl[1], tid));
  }

  // epilogue: bias + activation + store
#pragma unroll
  for (int m = 0; m < 4; ++m) {
    const long r0 = bm + wr * 64 + m * 16 + lk * 4;
#pragma unroll
    for (int n = 0; n < 8; ++n) {
      const long col = bn + wc * 128 + n * 16 + lr;
      const float bv = bias[col];
#pragma unroll
      for (int j = 0; j < 4; ++j) {
        float v = acc[m][n][j] + bv;
        if (RELU) v = fmaxf(v, 0.0f);
        if (OUTF32) ((float*)Cout)[(r0 + j) * (long)N + col] = v;
        else        ((u16*)Cout)[(r0 + j) * (long)N + col] = f2bf(v);
      }
    }
  }
}

// ======== gathered expert GEMM, same structure ========
__global__ __launch_bounds__(512, 2) void gemm256e(
    const u16* __restrict__ X, const u16* __restrict__ Wt,
    const float* __restrict__ bexp, u16* __restrict__ Out,
    const int* __restrict__ perm, const int* __restrict__ cvec,
    int K, int N, int TPE) {
  __shared__ u16 Al[2][256 * 64];
  __shared__ u16 Bl[2][256 * 64];
  const int e = blockIdx.x / TPE;
  const int tile = blockIdx.x - e * TPE;
  const int cnt = cvec[e];
  if (tile * 256 >= cnt) return;
  const int start = cvec[8 + e];

  const int tid = threadIdx.x;
  const int lane = tid & 63, wid = tid >> 6;
  const int wr = wid >> 1, wc = wid & 1;  // 4M x 2N
  const int lr = lane & 15, lk = lane >> 4;
  const long bn = (long)blockIdx.y << 8;
  const long wbase = (long)e * N;  // weight row base for this expert

  // preload gathered A-row indices (fixed per thread)
  long ar[2][2];
#pragma unroll
  for (int g = 0; g < 2; ++g)
#pragma unroll
    for (int j = 0; j < 2; ++j) {
      int rie = tile * 256 + ((j << 7) | (g << 6) | ((tid >> 3) & 63));
      ar[g][j] = perm[start + (rie < cnt - 1 ? rie : cnt - 1)];
    }

  const int nt = K >> 6;  // K=2048 -> 32, even
  f32x4 acc[4][8] = {};
  s16x8 a[4][2], bA[2][2], bB[2][2];

  stageAg(X, K, 0, 0, ar[0], Al[0], tid);
  stageB(Wt, K, wbase + bn, 0, 0, Bl[0], tid);
  stageB(Wt, K, wbase + bn, 0, 1, Bl[0], tid);
  stageAg(X, K, 0, 1, ar[1], Al[0], tid);
  stageAg(X, K, 64, 0, ar[0], Al[1], tid);
  stageB(Wt, K, wbase + bn, 64, 0, Bl[1], tid);
  stageB(Wt, K, wbase + bn, 64, 1, Bl[1], tid);
  VMCNT(6);
  BAR();

#pragma unroll
  for (int m = 0; m < 4; ++m)
#pragma unroll
    for (int ks = 0; ks < 2; ++ks)
      a[m][ks] = ldfrag(Al[0], wr * 64 + m * 16 + lr, ks, lk);
#pragma unroll
  for (int n = 0; n < 2; ++n)
#pragma unroll
    for (int ks = 0; ks < 2; ++ks)
      bA[n][ks] = ldfrag(Bl[0], wc * 128 + n * 16 + lr, ks, lk);

  const int ni = nt >> 1;
  for (int i2 = 0; i2 < ni; ++i2) {
    const int t0 = 2 * i2;
    const int kn1 = (t0 + 1) << 6;
    const int kn2 = ((t0 + 2 < nt) ? t0 + 2 : t0) << 6;
    const int kn3 = ((t0 + 3 < nt) ? t0 + 3 : t0 + 1) << 6;
    KT4(Al[0], Bl[0], Al[1], Bl[1],
        stageAg(X, K, kn1, 1, ar[1], Al[1], tid),
        stageAg(X, K, kn2, 0, ar[0], Al[0], tid),
        stageB(Wt, K, wbase + bn, kn2, 0, Bl[0], tid),
        stageB(Wt, K, wbase + bn, kn2, 1, Bl[0], tid));
    KT4(Al[1], Bl[1], Al[0], Bl[0],
        stageAg(X, K, kn2, 1, ar[1], Al[0], tid),
        stageAg(X, K, kn3, 0, ar[0], Al[1], tid),
        stageB(Wt, K, wbase + bn, kn3, 0, Bl[1], tid),
        stageB(Wt, K, wbase + bn, kn3, 1, Bl[1], tid));
  }

  // epilogue: bias + scatter via perm (guard rb < cnt)
#pragma unroll
  for (int m = 0; m < 4; ++m) {
    const int rb = tile * 256 + wr * 64 + m * 16 + lk * 4;
#pragma unroll
    for (int j = 0; j < 4; ++j) {
      if (rb + j < cnt) {
        const long grow = perm[start + rb + j];
#pragma unroll
        for (int n = 0; n < 8; ++n) {
          const long col = bn + wc * 128 + n * 16 + lr;
          float v = acc[m][n][j] + bexp[wbase + col];
          Out[grow * (long)N + col] = f2bf(v);
        }
      }
    }
  }
}

// ---------------- launch ----------------
extern "C" void kernel_launch(void* const* d_in, const int* in_sizes, int n_in,
                              void* d_out, int out_size, void* d_ws, size_t ws_size,
                              hipStream_t stream) {
  const float* x     = (const float*)d_in[0];
  const int*   kk    = (const int*)d_in[1];
  const float* W_exp = (const float*)d_in[2];
  const float* b_exp = (const float*)d_in[3];
  const float* W1    = (const float*)d_in[4];
  const float* b1    = (const float*)d_in[5];
  const float* W2    = (const float*)d_in[6];
  const float* b2    = (const float*)d_in[7];
  const float* W3    = (const float*)d_in[8];
  const float* b3    = (const float*)d_in[9];
  float* out = (float*)d_out;

  const int B = 16384, DIN = 2048, DC = 1024, H = 4096, DOUT = 1024, E = 4;

  uint8_t* ws = (uint8_t*)d_ws;
  const size_t MB = 1ull << 20;
  u16* xb    = (u16*)(ws + 0);         // 64MB  [B][2048]
  u16* algn  = (u16*)(ws + 64 * MB);   // 32MB  [B][1024]
  u16* h2    = (u16*)(ws + 0);         // 128MB [B][4096] (reuses xb+algn, live later)
  u16* h1    = (u16*)(ws + 128 * MB);  // 128MB [B][4096]
  u16* wexpt = (u16*)(ws + 256 * MB);  // 16MB  [4][1024][2048]
  u16* w1t   = (u16*)(ws + 272 * MB);  // 8MB   [4096][1024]
  u16* w2t   = (u16*)(ws + 280 * MB);  // 32MB  [4096][4096]
  u16* w3t   = (u16*)(ws + 312 * MB);  // 8MB   [1024][4096]
  int* perm  = (int*)(ws + 320 * MB);  // 64KB
  int* cvec  = (int*)(ws + 320 * MB + 65536);

  // router
  route_zero<<<1, 64, 0, stream>>>(cvec);
  route_count<<<(B + 255) / 256, 256, 0, stream>>>(kk, cvec, B);
  route_scan<<<1, 64, 0, stream>>>(cvec);
  route_scatter<<<(B + 255) / 256, 256, 0, stream>>>(kk, cvec, perm, B);

  // conversions
  cvt_f32_bf16<<<2048, 256, 0, stream>>>(x, xb, (long)B * DIN / 4);
  dim3 tb(32, 8);
  transpose_w<<<dim3(DC / 32, DIN / 32, E), tb, 0, stream>>>(W_exp, wexpt, DIN, DC);
  transpose_w<<<dim3(H / 32, DC / 32, 1), tb, 0, stream>>>(W1, w1t, DC, H);
  transpose_w<<<dim3(H / 32, H / 32, 1), tb, 0, stream>>>(W2, w2t, H, H);
  transpose_w<<<dim3(DOUT / 32, H / 32, 1), tb, 0, stream>>>(W3, w3t, H, DOUT);

  // expert projection (gathered, 256^2 8-phase, reads-early)
  const int TPE = B / 256;
  gemm256e<<<dim3(E * TPE, DC / 256), 512, 0, stream>>>(
      xb, wexpt, b_exp, algn, perm, cvec, DIN, DC, TPE);

  // dense MLP (reads-early schedule)
  gemm256p<1, 0><<<dim3((B / 256) * (H / 256)), 512, 0, stream>>>(algn, w1t, b1, h1, H, DC);
  gemm256p<1, 0><<<dim3((B / 256) * (H / 256)), 512, 0, stream>>>(h1, w2t, b2, h2, H, H);
  gemm256p<0, 1><<<dim3((B / 256) * (DOUT / 256)), 512, 0, stream>>>(h2, w3t, b3, out, DOUT, H);
}

// Round 12
// 1098.000 us; speedup vs baseline: 1.0749x; 1.0014x over previous
//
#include <hip/hip_runtime.h>
#include <stdint.h>

#define DEV static __device__ __forceinline__

typedef unsigned short u16;
typedef float  f32x4 __attribute__((ext_vector_type(4)));
typedef short  s16x8 __attribute__((ext_vector_type(8)));
typedef u16    u16x4 __attribute__((ext_vector_type(4)));

#define VMCNT(n) asm volatile("s_waitcnt vmcnt(" #n ")" ::: "memory")
#define BAR() __builtin_amdgcn_s_barrier()
#define SCHEDB() __builtin_amdgcn_sched_barrier(0)
#define MFMA16(d, va, vb) d = __builtin_amdgcn_mfma_f32_16x16x32_bf16(va, vb, d, 0, 0, 0)

// round-to-nearest-even f32 -> bf16 bits
DEV u16 f2bf(float f) {
  uint32_t u = __float_as_uint(f);
  u += 0x7FFFu + ((u >> 16) & 1u);
  return (u16)(u >> 16);
}

// async global->LDS, 16 bytes per lane
DEV void async16(const void* g, void* l) {
  __builtin_amdgcn_global_load_lds(
      (const __attribute__((address_space(1))) void*)g,
      (__attribute__((address_space(3))) void*)l, 16, 0, 0);
}

// ---------------- router ----------------
__global__ void route_zero(int* c) {
  if (threadIdx.x < 8) c[threadIdx.x] = 0;
}
__global__ void route_count(const int* __restrict__ k, int* __restrict__ c, int B) {
  int i = blockIdx.x * blockDim.x + threadIdx.x;
  if (i < B) atomicAdd(&c[k[i]], 1);
}
__global__ void route_scan(int* c) {
  if (threadIdx.x == 0) {
    int s = 0;
    for (int e = 0; e < 4; ++e) { c[8 + e] = s; s += c[e]; }
  }
}
__global__ void route_scatter(const int* __restrict__ k, int* __restrict__ c,
                              int* __restrict__ perm, int B) {
  int i = blockIdx.x * blockDim.x + threadIdx.x;
  if (i < B) {
    int e = k[i];
    int pos = atomicAdd(&c[4 + e], 1);
    perm[c[8 + e] + pos] = i;
  }
}

// ---------------- conversions ----------------
__global__ void cvt_f32_bf16(const float* __restrict__ src, u16* __restrict__ dst, long n4) {
  long i = (long)blockIdx.x * blockDim.x + threadIdx.x;
  long stride = (long)gridDim.x * blockDim.x;
  for (; i < n4; i += stride) {
    f32x4 v = ((const f32x4*)src)[i];
    u16x4 o;
    o.x = f2bf(v.x); o.y = f2bf(v.y); o.z = f2bf(v.z); o.w = f2bf(v.w);
    ((u16x4*)dst)[i] = o;
  }
}

// src [z][R][C] f32  ->  dst [z][C][R] bf16
__global__ void transpose_w(const float* __restrict__ src, u16* __restrict__ dst,
                            int R, int C) {
  __shared__ float t[32][33];
  long base = (long)blockIdx.z * R * C;
  int c0 = blockIdx.x * 32, r0 = blockIdx.y * 32;
  int tx = threadIdx.x, ty = threadIdx.y;  // (32,8)
#pragma unroll
  for (int i = 0; i < 32; i += 8)
    t[ty + i][tx] = src[base + (long)(r0 + ty + i) * C + c0 + tx];
  __syncthreads();
#pragma unroll
  for (int i = 0; i < 32; i += 8)
    dst[base + (long)(c0 + ty + i) * R + r0 + tx] = f2bf(t[tx][ty + i]);
}

// ======== 256x256 8-phase GEMM, reads-early + sched_barrier pin ========
// A [M][K] bf16, Bt [N][K] bf16, C = act(A @ Bt^T + bias)
// 512 threads = 8 waves (4M x 2N), per-wave 64x128. BK=64. LDS 128KB.
// Rows 128B, XOR swizzle byte ^= (row&7)<<4 (inverse on global source);
// measured 0 bank conflicts.
// Round-12 change: sched_barrier(0) after each early B-pair ds_read block
// pins the reads BEFORE the MFMA cluster (round-11 null showed the
// compiler sank them to their consumers, defeating the overlap). The
// cluster's lgkm wait is then lgkmcnt(4) (older reads), non-blocking for
// the just-issued pair, whose latency hides under ~620cy of MFMA.
// Stage schedule & vmcnt(6) ledger identical to verified round-7/9:
// P1 Ah1(t+1), P2 Ah0(t+2), P3 Bh0(t+2), P4 Bh1(t+2)+vmcnt(6), mirrored.

DEV void stageA(const u16* __restrict__ A, long K, long bm, int k0, int g,
                u16* lds, int tid) {
#pragma unroll
  for (int j = 0; j < 2; ++j) {
    int i = j * 512 + tid;
    int row = ((i >> 9) << 7) | (g << 6) | ((i >> 3) & 63);
    int p = (i & 7) * 16;                  // phys byte-in-row
    int ke = (p ^ ((row & 7) << 4)) >> 1;  // logical k element (inverse swizzle)
    async16(A + (bm + row) * K + k0 + ke, lds + row * 64 + (i & 7) * 8);
  }
}

DEV void stageB(const u16* __restrict__ Bt, long K, long bn, int k0, int g,
                u16* lds, int tid) {
#pragma unroll
  for (int j = 0; j < 2; ++j) {
    int i = j * 512 + tid;
    int col = ((i >> 8) << 6) | (g << 5) | ((i >> 3) & 31);
    int p = (i & 7) * 16;
    int ke = (p ^ ((col & 7) << 4)) >> 1;
    async16(Bt + (bn + col) * K + k0 + ke, lds + col * 64 + (i & 7) * 8);
  }
}

// gathered A staging: per-thread global rows preloaded (ar[j]), LDS row from tid
DEV void stageAg(const u16* __restrict__ X, long K, int k0, int g,
                 const long* ar, u16* lds, int tid) {
#pragma unroll
  for (int j = 0; j < 2; ++j) {
    int i = j * 512 + tid;
    int row = (j << 7) | (g << 6) | ((i >> 3) & 63);
    int p = (i & 7) * 16;
    int ke = (p ^ ((row & 7) << 4)) >> 1;
    async16(X + ar[j] * K + k0 + ke, lds + row * 64 + (i & 7) * 8);
  }
}

DEV s16x8 ldfrag(const u16* lds, int row, int ks, int lk) {
  int b = (ks * 64 + lk * 16) ^ ((row & 7) << 4);
  return *(const s16x8*)((const char*)(lds + row * 64) + b);
}

// One K-tile = 4 phases. Entering: a = A(t), bA = B cols nf0-1 of t.
// Phase: [stage; (vmcnt); BAR; early-read next b-pair; SCHED_BARRIER;
// MFMA x16]. P4 late-reads a' (WAR-pinned after its cluster).
#define KT4(Ac, Bc, An, Bn, S1, S2, S3, S4)                                    \
  {                                                                            \
    /* P1: MFMA a x bA(nf0-1) -> acc[:,0:2]; read bB = nf2-3 */                \
    S1;                                                                        \
    BAR();                                                                     \
    _Pragma("unroll") for (int n = 0; n < 2; ++n)                              \
      _Pragma("unroll") for (int ks = 0; ks < 2; ++ks)                         \
        bB[n][ks] = ldfrag(Bc, wc * 128 + (n + 2) * 16 + lr, ks, lk);          \
    SCHEDB();                                                                  \
    __builtin_amdgcn_s_setprio(1);                                             \
    _Pragma("unroll") for (int m = 0; m < 4; ++m)                              \
      _Pragma("unroll") for (int n = 0; n < 2; ++n)                            \
        _Pragma("unroll") for (int ks = 0; ks < 2; ++ks)                       \
          MFMA16(acc[m][n], a[m][ks], bA[n][ks]);                              \
    __builtin_amdgcn_s_setprio(0);                                             \
    /* P2: MFMA a x bB(nf2-3) -> acc[:,2:4]; read bA = nf4-5 */                \
    S2;                                                                        \
    BAR();                                                                     \
    _Pragma("unroll") for (int n = 0; n < 2; ++n)                              \
      _Pragma("unroll") for (int ks = 0; ks < 2; ++ks)                         \
        bA[n][ks] = ldfrag(Bc, wc * 128 + (n + 4) * 16 + lr, ks, lk);          \
    SCHEDB();                                                                  \
    __builtin_amdgcn_s_setprio(1);                                             \
    _Pragma("unroll") for (int m = 0; m < 4; ++m)                              \
      _Pragma("unroll") for (int n = 0; n < 2; ++n)                            \
        _Pragma("unroll") for (int ks = 0; ks < 2; ++ks)                       \
          MFMA16(acc[m][n + 2], a[m][ks], bB[n][ks]);                          \
    __builtin_amdgcn_s_setprio(0);                                             \
    /* P3: MFMA a x bA(nf4-5) -> acc[:,4:6]; read bB = nf6-7 */                \
    S3;                                                                        \
    BAR();                                                                     \
    _Pragma("unroll") for (int n = 0; n < 2; ++n)                              \
      _Pragma("unroll") for (int ks = 0; ks < 2; ++ks)                         \
        bB[n][ks] = ldfrag(Bc, wc * 128 + (n + 6) * 16 + lr, ks, lk);          \
    SCHEDB();                                                                  \
    __builtin_amdgcn_s_setprio(1);                                             \
    _Pragma("unroll") for (int m = 0; m < 4; ++m)                              \
      _Pragma("unroll") for (int n = 0; n < 2; ++n)                            \
        _Pragma("unroll") for (int ks = 0; ks < 2; ++ks)                       \
          MFMA16(acc[m][n + 4], a[m][ks], bA[n][ks]);                          \
    __builtin_amdgcn_s_setprio(0);                                             \
    /* P4: read bA = nf0-1 of NEXT tile (Bn, certified by vmcnt+BAR);          \
       MFMA a x bB(nf6-7) -> acc[:,6:8]; late-read a' from An */               \
    S4;                                                                        \
    VMCNT(6);                                                                  \
    BAR();                                                                     \
    _Pragma("unroll") for (int n = 0; n < 2; ++n)                              \
      _Pragma("unroll") for (int ks = 0; ks < 2; ++ks)                         \
        bA[n][ks] = ldfrag(Bn, wc * 128 + n * 16 + lr, ks, lk);                \
    SCHEDB();                                                                  \
    __builtin_amdgcn_s_setprio(1);                                             \
    _Pragma("unroll") for (int m = 0; m < 4; ++m)                              \
      _Pragma("unroll") for (int n = 0; n < 2; ++n)                            \
        _Pragma("unroll") for (int ks = 0; ks < 2; ++ks)                       \
          MFMA16(acc[m][n + 6], a[m][ks], bB[n][ks]);                          \
    __builtin_amdgcn_s_setprio(0);                                             \
    _Pragma("unroll") for (int m = 0; m < 4; ++m)                              \
      _Pragma("unroll") for (int ks = 0; ks < 2; ++ks)                         \
        a[m][ks] = ldfrag(An, wr * 64 + m * 16 + lr, ks, lk);                  \
  }

template <int RELU, int OUTF32>
__global__ __launch_bounds__(512, 2) void gemm256p(
    const u16* __restrict__ A, const u16* __restrict__ Bt,
    const float* __restrict__ bias, void* __restrict__ Cout, int N, int K) {
  __shared__ u16 Al[2][256 * 64];
  __shared__ u16 Bl[2][256 * 64];
  const int tid = threadIdx.x;
  const int lane = tid & 63, wid = tid >> 6;
  const int wr = wid >> 1, wc = wid & 1;  // 4M x 2N wave grid
  const int lr = lane & 15, lk = lane >> 4;

  // XCD-aware bijective swizzle (grids all % 8 == 0; guarded)
  const int nby = N >> 8;
  const int nwg = gridDim.x;
  int wg = blockIdx.x;
  if ((nwg & 7) == 0) {
    const int q = nwg >> 3;
    wg = (wg & 7) * q + (wg >> 3);
  }
  const long bm = (long)(wg / nby) << 8;
  const long bn = (long)(wg % nby) << 8;

  const int nt = K >> 6;  // even (>=16) for all K used here
  f32x4 acc[4][8] = {};
  s16x8 a[4][2], bA[2][2], bB[2][2];

  // prologue: tile0 fully + tile1 halves Ah0,Bh0,Bh1 (Ah1(1) staged at P1)
  stageA(A, K, bm, 0, 0, Al[0], tid);
  stageB(Bt, K, bn, 0, 0, Bl[0], tid);
  stageB(Bt, K, bn, 0, 1, Bl[0], tid);
  stageA(A, K, bm, 0, 1, Al[0], tid);
  stageA(A, K, bm, 64, 0, Al[1], tid);
  stageB(Bt, K, bn, 64, 0, Bl[1], tid);
  stageB(Bt, K, bn, 64, 1, Bl[1], tid);
  VMCNT(6);  // drains tile0's 8 loads; leaves tile1's 3 halves (steady state)
  BAR();

  // initial frags: a = A(tile0), bA = B cols nf0-1 (tile0)
#pragma unroll
  for (int m = 0; m < 4; ++m)
#pragma unroll
    for (int ks = 0; ks < 2; ++ks)
      a[m][ks] = ldfrag(Al[0], wr * 64 + m * 16 + lr, ks, lk);
#pragma unroll
  for (int n = 0; n < 2; ++n)
#pragma unroll
    for (int ks = 0; ks < 2; ++ks)
      bA[n][ks] = ldfrag(Bl[0], wc * 128 + n * 16 + lr, ks, lk);

  const int ni = nt >> 1;
  for (int i2 = 0; i2 < ni; ++i2) {
    const int t0 = 2 * i2;
    const int kn1 = (t0 + 1) << 6;  // fresh stage of Ah1(t+1)
    const int kn2 = ((t0 + 2 < nt) ? t0 + 2 : t0) << 6;       // clamped re-stage
    const int kn3 = ((t0 + 3 < nt) ? t0 + 3 : t0 + 1) << 6;
    KT4(Al[0], Bl[0], Al[1], Bl[1],
        stageA(A, K, bm, kn1, 1, Al[1], tid),
        stageA(A, K, bm, kn2, 0, Al[0], tid),
        stageB(Bt, K, bn, kn2, 0, Bl[0], tid),
        stageB(Bt, K, bn, kn2, 1, Bl[0], tid));
    KT4(Al[1], Bl[1], Al[0], Bl[0],
        stageA(A, K, bm, kn2, 1, Al[0], tid),
        stageA(A, K, bm, kn3, 0, Al[1], tid),
        stageB(Bt, K, bn, kn3, 0, Bl[1], tid),
        stageB(Bt, K, bn, kn3, 1, Bl[1], tid));
  }

  // epilogue: bias + activation + store
#pragma unroll
  for (int m = 0; m < 4; ++m) {
    const long r0 = bm + wr * 64 + m * 16 + lk * 4;
#pragma unroll
    for (int n = 0; n < 8; ++n) {
      const long col = bn + wc * 128 + n * 16 + lr;
      const float bv = bias[col];
#pragma unroll
      for (int j = 0; j < 4; ++j) {
        float v = acc[m][n][j] + bv;
        if (RELU) v = fmaxf(v, 0.0f);
        if (OUTF32) ((float*)Cout)[(r0 + j) * (long)N + col] = v;
        else        ((u16*)Cout)[(r0 + j) * (long)N + col] = f2bf(v);
      }
    }
  }
}

// ======== gathered expert GEMM, same structure ========
__global__ __launch_bounds__(512, 2) void gemm256e(
    const u16* __restrict__ X, const u16* __restrict__ Wt,
    const float* __restrict__ bexp, u16* __restrict__ Out,
    const int* __restrict__ perm, const int* __restrict__ cvec,
    int K, int N, int TPE) {
  __shared__ u16 Al[2][256 * 64];
  __shared__ u16 Bl[2][256 * 64];
  const int e = blockIdx.x / TPE;
  const int tile = blockIdx.x - e * TPE;
  const int cnt = cvec[e];
  if (tile * 256 >= cnt) return;
  const int start = cvec[8 + e];

  const int tid = threadIdx.x;
  const int lane = tid & 63, wid = tid >> 6;
  const int wr = wid >> 1, wc = wid & 1;  // 4M x 2N
  const int lr = lane & 15, lk = lane >> 4;
  const long bn = (long)blockIdx.y << 8;
  const long wbase = (long)e * N;  // weight row base for this expert

  // preload gathered A-row indices (fixed per thread)
  long ar[2][2];
#pragma unroll
  for (int g = 0; g < 2; ++g)
#pragma unroll
    for (int j = 0; j < 2; ++j) {
      int rie = tile * 256 + ((j << 7) | (g << 6) | ((tid >> 3) & 63));
      ar[g][j] = perm[start + (rie < cnt - 1 ? rie : cnt - 1)];
    }

  const int nt = K >> 6;  // K=2048 -> 32, even
  f32x4 acc[4][8] = {};
  s16x8 a[4][2], bA[2][2], bB[2][2];

  stageAg(X, K, 0, 0, ar[0], Al[0], tid);
  stageB(Wt, K, wbase + bn, 0, 0, Bl[0], tid);
  stageB(Wt, K, wbase + bn, 0, 1, Bl[0], tid);
  stageAg(X, K, 0, 1, ar[1], Al[0], tid);
  stageAg(X, K, 64, 0, ar[0], Al[1], tid);
  stageB(Wt, K, wbase + bn, 64, 0, Bl[1], tid);
  stageB(Wt, K, wbase + bn, 64, 1, Bl[1], tid);
  VMCNT(6);
  BAR();

#pragma unroll
  for (int m = 0; m < 4; ++m)
#pragma unroll
    for (int ks = 0; ks < 2; ++ks)
      a[m][ks] = ldfrag(Al[0], wr * 64 + m * 16 + lr, ks, lk);
#pragma unroll
  for (int n = 0; n < 2; ++n)
#pragma unroll
    for (int ks = 0; ks < 2; ++ks)
      bA[n][ks] = ldfrag(Bl[0], wc * 128 + n * 16 + lr, ks, lk);

  const int ni = nt >> 1;
  for (int i2 = 0; i2 < ni; ++i2) {
    const int t0 = 2 * i2;
    const int kn1 = (t0 + 1) << 6;
    const int kn2 = ((t0 + 2 < nt) ? t0 + 2 : t0) << 6;
    const int kn3 = ((t0 + 3 < nt) ? t0 + 3 : t0 + 1) << 6;
    KT4(Al[0], Bl[0], Al[1], Bl[1],
        stageAg(X, K, kn1, 1, ar[1], Al[1], tid),
        stageAg(X, K, kn2, 0, ar[0], Al[0], tid),
        stageB(Wt, K, wbase + bn, kn2, 0, Bl[0], tid),
        stageB(Wt, K, wbase + bn, kn2, 1, Bl[0], tid));
    KT4(Al[1], Bl[1], Al[0], Bl[0],
        stageAg(X, K, kn2, 1, ar[1], Al[0], tid),
        stageAg(X, K, kn3, 0, ar[0], Al[1], tid),
        stageB(Wt, K, wbase + bn, kn3, 0, Bl[1], tid),
        stageB(Wt, K, wbase + bn, kn3, 1, Bl[1], tid));
  }

  // epilogue: bias + scatter via perm (guard rb < cnt)
#pragma unroll
  for (int m = 0; m < 4; ++m) {
    const int rb = tile * 256 + wr * 64 + m * 16 + lk * 4;
#pragma unroll
    for (int j = 0; j < 4; ++j) {
      if (rb + j < cnt) {
        const long grow = perm[start + rb + j];
#pragma unroll
        for (int n = 0; n < 8; ++n) {
          const long col = bn + wc * 128 + n * 16 + lr;
          float v = acc[m][n][j] + bexp[wbase + col];
          Out[grow * (long)N + col] = f2bf(v);
        }
      }
    }
  }
}

// ---------------- launch ----------------
extern "C" void kernel_launch(void* const* d_in, const int* in_sizes, int n_in,
                              void* d_out, int out_size, void* d_ws, size_t ws_size,
                              hipStream_t stream) {
  const float* x     = (const float*)d_in[0];
  const int*   kk    = (const int*)d_in[1];
  const float* W_exp = (const float*)d_in[2];
  const float* b_exp = (const float*)d_in[3];
  const float* W1    = (const float*)d_in[4];
  const float* b1    = (const float*)d_in[5];
  const float* W2    = (const float*)d_in[6];
  const float* b2    = (const float*)d_in[7];
  const float* W3    = (const float*)d_in[8];
  const float* b3    = (const float*)d_in[9];
  float* out = (float*)d_out;

  const int B = 16384, DIN = 2048, DC = 1024, H = 4096, DOUT = 1024, E = 4;

  uint8_t* ws = (uint8_t*)d_ws;
  const size_t MB = 1ull << 20;
  u16* xb    = (u16*)(ws + 0);         // 64MB  [B][2048]
  u16* algn  = (u16*)(ws + 64 * MB);   // 32MB  [B][1024]
  u16* h2    = (u16*)(ws + 0);         // 128MB [B][4096] (reuses xb+algn, live later)
  u16* h1    = (u16*)(ws + 128 * MB);  // 128MB [B][4096]
  u16* wexpt = (u16*)(ws + 256 * MB);  // 16MB  [4][1024][2048]
  u16* w1t   = (u16*)(ws + 272 * MB);  // 8MB   [4096][1024]
  u16* w2t   = (u16*)(ws + 280 * MB);  // 32MB  [4096][4096]
  u16* w3t   = (u16*)(ws + 312 * MB);  // 8MB   [1024][4096]
  int* perm  = (int*)(ws + 320 * MB);  // 64KB
  int* cvec  = (int*)(ws + 320 * MB + 65536);

  // router
  route_zero<<<1, 64, 0, stream>>>(cvec);
  route_count<<<(B + 255) / 256, 256, 0, stream>>>(kk, cvec, B);
  route_scan<<<1, 64, 0, stream>>>(cvec);
  route_scatter<<<(B + 255) / 256, 256, 0, stream>>>(kk, cvec, perm, B);

  // conversions
  cvt_f32_bf16<<<2048, 256, 0, stream>>>(x, xb, (long)B * DIN / 4);
  dim3 tb(32, 8);
  transpose_w<<<dim3(DC / 32, DIN / 32, E), tb, 0, stream>>>(W_exp, wexpt, DIN, DC);
  transpose_w<<<dim3(H / 32, DC / 32, 1), tb, 0, stream>>>(W1, w1t, DC, H);
  transpose_w<<<dim3(H / 32, H / 32, 1), tb, 0, stream>>>(W2, w2t, H, H);
  transpose_w<<<dim3(DOUT / 32, H / 32, 1), tb, 0, stream>>>(W3, w3t, H, DOUT);

  // expert projection (gathered, 256^2 8-phase, reads-early+pin)
  const int TPE = B / 256;
  gemm256e<<<dim3(E * TPE, DC / 256), 512, 0, stream>>>(
      xb, wexpt, b_exp, algn, perm, cvec, DIN, DC, TPE);

  // dense MLP (reads-early + sched_barrier pin)
  gemm256p<1, 0><<<dim3((B / 256) * (H / 256)), 512, 0, stream>>>(algn, w1t, b1, h1, H, DC);
  gemm256p<1, 0><<<dim3((B / 256) * (H / 256)), 512, 0, stream>>>(h1, w2t, b2, h2, H, H);
  gemm256p<0, 1><<<dim3((B / 256) * (DOUT / 256)), 512, 0, stream>>>(h2, w3t, b3, out, DOUT, H);
}